// Round 6
// baseline (183.220 us; speedup 1.0000x reference)
//
#include <hip/hip_runtime.h>

// Round 12: 3-buffer rotation, 2-deep prefetch, ONE barrier per kt.
//  R7-R11 ordering proved prefetch depth is the binding variable (1-deep=48,
//  0-deep=54/66, none=100) and occupancy is NOT (R9: 30 waves/CU < 15).
//  Scheme per kt: [counted waitvm(S) -> s_barrier -> issue stage(kt+2) into
//  buf[(kt+2)%3] -> ds_read+MFMA on buf[kt%3]]. Two compute phases of load
//  lead time; write-after-read hazard is 3 iters out, so the read-done
//  barrier of R8 is subsumed by the next land-barrier: 16 barriers (was 32).
//  Per-wave S: d5 w0-3=5,w4=4; d3 w0-2=5,w3=1,w4=0; d1 w0-3=4,w4=0.
//  LDS 3 x 24KB = 72KB -> 2 blocks/CU (occupancy loss proven cheap).
//  Keeps: gld16, T2 both-sides XOR swizzle, XCD-chunked bijective block
//  swizzle, setprio, Cs LDS-interleave epilogue. prep (L1) unchanged.

#define BATCH 4096
#define DTOT 4608
#define NMUL 512
#define BSTRIDE 12288   // u16 per LDS buffer (24 KiB): A 10240 + B 2048

typedef __attribute__((ext_vector_type(8))) short short8;
typedef __attribute__((ext_vector_type(8))) unsigned short ushort8;
typedef __attribute__((ext_vector_type(4))) float float4v;

#define XPL_BYTES (9ull * BATCH * NMUL * 2)

__device__ __forceinline__ unsigned short f2bf(float f) {
    unsigned int u = __builtin_bit_cast(unsigned int, f);
    return (unsigned short)((u + 0x7fffu + ((u >> 16) & 1u)) >> 16);
}
__device__ __forceinline__ void gld16(const unsigned short* g, unsigned short* l) {
    __builtin_amdgcn_global_load_lds(
        (const __attribute__((address_space(1))) unsigned int*)(const void*)g,
        (__attribute__((address_space(3))) unsigned int*)(void*)l, 16, 0, 0);
}
template <int N>
__device__ __forceinline__ void waitvm() {
    asm volatile("s_waitcnt vmcnt(%0)" :: "n"(N) : "memory");
}
__device__ __forceinline__ void colmap(int col, int& c, int& u) {
    if (col < 512)       { c = 0; u = col; }
    else if (col < 2048) { int t = col - 512;  c = 1 + t % 3; u = t / 3; }
    else                 { int t = col - 2048; c = 4 + t % 5; u = t / 5; }
}

// ---- L1: prep (deint rows + W convert tiles) — unchanged ----
__global__ __launch_bounds__(256) void prep(const float* __restrict__ x,
                                            const float* __restrict__ w0,
                                            const float* __restrict__ w1,
                                            const float* __restrict__ w2,
                                            unsigned short* __restrict__ Xp,
                                            unsigned short* __restrict__ Wt) {
    __shared__ unsigned short buf[4608];
    const int tid = threadIdx.x;
    const int b = blockIdx.x;
    if (b < BATCH) {
        const int row = b;
        const float4v* src = (const float4v*)(x + (size_t)row * DTOT);
        for (int p = tid; p < DTOT / 4; p += 256) {
            float4v v = src[p];
#pragma unroll
            for (int j = 0; j < 4; ++j) {
                int c, u; colmap(p * 4 + j, c, u);
                buf[c * NMUL + u] = f2bf(v[j]);
            }
        }
        __syncthreads();
        for (int q = tid; q < DTOT / 8; q += 256) {
            const int c = q >> 6, u8 = q & 63;
            *(ushort8*)(Xp + ((size_t)(c * BATCH + row) * NMUL) + u8 * 8) =
                *(const ushort8*)&buf[c * NMUL + u8 * 8];
        }
    } else {
        const int t = b - BATCH;              // 0..191
        const int ch = t >> 6, tt = t & 63;
        const int tk = (tt >> 3) * 64, tn = (tt & 7) * 64;
        const float* W = (ch == 0) ? w0 : (ch == 1) ? w1 : w2;
        const int r0 = tid >> 4, c4 = (tid & 15) * 4;
#pragma unroll
        for (int rr = 0; rr < 4; ++rr) {
            const int row = r0 + rr * 16;     // k within tile
            float4v v = *(const float4v*)(W + (size_t)(tk + row) * NMUL + tn + c4);
#pragma unroll
            for (int j = 0; j < 4; ++j) buf[(c4 + j) * 72 + row] = f2bf(v[j]);
        }
        __syncthreads();
        for (int q = tid; q < 512; q += 256) {
            const int nn = q >> 3, k8 = q & 7;
            *(ushort8*)(Wt + ((size_t)(ch * NMUL + tn + nn) * NMUL) + tk + k8 * 8) =
                *(const ushort8*)&buf[nn * 72 + k8 * 8];
        }
    }
}

// ---- d in {3,5}: 64x64xD, wave=plane, 3-buf 2-deep, 1 barrier/kt ----
template <int D, int PBASE, int XOFF, int WCH>
__device__ __forceinline__ void body_d35(int rel,
                                         const unsigned short* __restrict__ Xp,
                                         const unsigned short* __restrict__ Wt,
                                         float* __restrict__ out,
                                         unsigned short* LDS) {
    const int tid = threadIdx.x;
    const int lane = tid & 63;
    const int w = tid >> 6;                   // 0..4; planes use 0..D-1
    const int lr = lane & 15;
    const int lq = lane >> 4;

    const int n0 = (rel & 7) * 64;
    const int m0 = (rel >> 3) * 64;

    const int ksw = ((lane & 3) ^ ((lane >> 3) & 3)) * 8;
    const int rsw = (lq ^ ((lr >> 1) & 3)) * 8;

    const unsigned short* Ag =
        Xp + ((size_t)(PBASE + w) * BATCH + m0 + (lane >> 2)) * NMUL + ksw;
    const unsigned short* Bg =
        Wt + ((size_t)WCH * NMUL + n0 + (lane >> 2)) * NMUL + ksw;

    float4v acc[4][4];
#pragma unroll
    for (int a = 0; a < 4; ++a)
#pragma unroll
        for (int b = 0; b < 4; ++b) acc[a][b] = (float4v)0.f;

    auto stage = [&](int ko, int bo) {
        if (w < D) {
#pragma unroll
            for (int p = 0; p < 4; ++p)
                gld16(Ag + (size_t)p * 16 * NMUL + ko, LDS + bo + w * 2048 + p * 512);
        }
        if (w < 4)
            gld16(Bg + (size_t)w * 16 * NMUL + ko, LDS + bo + 10240 + w * 512);
    };

    stage(0, 0);                  // kt=0 -> buf0
    stage(32, BSTRIDE);           // kt=1 -> buf1

    int co = 0, po = 2 * BSTRIDE;
    for (int kt = 0; kt < 16; ++kt) {
        // (a) counted wait: own stage(kt) landed; stage(kt+1) stays in flight
        if (kt == 15) { waitvm<0>(); }
        else if (D == 5) { if (w < 4) waitvm<5>(); else waitvm<4>(); }
        else             { if (w < 3) waitvm<5>(); else if (w == 3) waitvm<1>(); }
        // (b) land-barrier (also the deferred write-hazard barrier for kt+2)
        __builtin_amdgcn_s_barrier();
        // (c) 2-ahead prefetch
        if (kt < 14) stage((kt + 2) * 32, po);
        // (d) compute buf[kt%3]
        if (w < D) {
            const unsigned short* Al = LDS + co + w * 2048;
            const unsigned short* Bl = LDS + co + 10240;
            short8 af[4], bf[4];
#pragma unroll
            for (int mi = 0; mi < 4; ++mi)
                af[mi] = *(const short8*)(Al + (mi * 16 + lr) * 32 + rsw);
#pragma unroll
            for (int ni = 0; ni < 4; ++ni)
                bf[ni] = *(const short8*)(Bl + (ni * 16 + lr) * 32 + rsw);
            __builtin_amdgcn_s_setprio(1);
#pragma unroll
            for (int mi = 0; mi < 4; ++mi)
#pragma unroll
                for (int ni = 0; ni < 4; ++ni)
                    acc[mi][ni] = __builtin_amdgcn_mfma_f32_16x16x32_bf16(
                        af[mi], bf[ni], acc[mi][ni], 0, 0, 0);
            __builtin_amdgcn_s_setprio(0);
        }
        co += BSTRIDE; if (co == 3 * BSTRIDE) co = 0;
        po += BSTRIDE; if (po == 3 * BSTRIDE) po = 0;
    }

    // epilogue: Cs LDS-interleave (verified R5-R8); Cs overlays buffer 0
    float* Cs = (float*)LDS;
    const float PW = 0.044194173824159216f;
    __syncthreads();              // all waves done reading K-loop buffers
#pragma unroll
    for (int mc = 0; mc < 4; ++mc) {
        if (w < D) {
#pragma unroll
            for (int ni = 0; ni < 4; ++ni)
#pragma unroll
                for (int r = 0; r < 4; ++r)
                    Cs[(lq * 4 + r) * (64 * D) + (ni * 16 + lr) * D + w] =
                        acc[mc][ni][r] * PW;
        }
        __syncthreads();
        constexpr int F4 = 16 * 16 * D;
        for (int f = tid; f < F4; f += 320) {
            const int row = f / (16 * D);
            const int c4  = f % (16 * D);
            *(float4v*)(out + (size_t)(m0 + mc * 16 + row) * DTOT + XOFF + n0 * D + c4 * 4) =
                *(const float4v*)(Cs + f * 4);
        }
        __syncthreads();
    }
}

// ---- d=1: 128x128, waves 0..3 (wave 4 barriers only), 3-buf 2-deep ----
// Per buffer: A at bo (4096 u16), B at bo+4096 (4096 u16).
__device__ __forceinline__ void body_d1(int rel,
                                        const unsigned short* __restrict__ Xp,
                                        const unsigned short* __restrict__ Wt,
                                        const float* __restrict__ b0,
                                        float* __restrict__ out,
                                        unsigned short* LDS) {
    const int tid = threadIdx.x;
    const int lane = tid & 63;
    const int w = tid >> 6;
    const int lr = lane & 15;
    const int lq = lane >> 4;
    const int wm = (w >> 1) * 64;
    const int wn = (w & 1) * 64;

    const int n0 = (rel & 3) * 128;
    const int m0 = (rel >> 2) * 128;

    const int ksw = ((lane & 3) ^ ((lane >> 3) & 3)) * 8;
    const int rsw = (lq ^ ((lr >> 1) & 3)) * 8;

    const unsigned short* Ag = Xp + (size_t)(m0 + w * 32 + (lane >> 2)) * NMUL + ksw;
    const unsigned short* Bg = Wt + (size_t)(n0 + w * 32 + (lane >> 2)) * NMUL + ksw;

    float4v acc[4][4];
#pragma unroll
    for (int a = 0; a < 4; ++a)
#pragma unroll
        for (int b = 0; b < 4; ++b) acc[a][b] = (float4v)0.f;

    auto stage = [&](int ko, int bo) {
        if (w < 4) {
            gld16(Ag + ko, LDS + bo + w * 1024);
            gld16(Ag + ko + 16 * NMUL, LDS + bo + w * 1024 + 512);
            gld16(Bg + ko, LDS + bo + 4096 + w * 1024);
            gld16(Bg + ko + 16 * NMUL, LDS + bo + 4096 + w * 1024 + 512);
        }
    };

    stage(0, 0);
    stage(32, BSTRIDE);

    int co = 0, po = 2 * BSTRIDE;
    for (int kt = 0; kt < 16; ++kt) {
        if (kt == 15) { waitvm<0>(); }
        else if (w < 4) waitvm<4>();
        __builtin_amdgcn_s_barrier();
        if (kt < 14) stage((kt + 2) * 32, po);
        if (w < 4) {
            const unsigned short* Ab = LDS + co;
            const unsigned short* Bb = LDS + co + 4096;
            short8 af[4], bf[4];
#pragma unroll
            for (int mi = 0; mi < 4; ++mi)
                af[mi] = *(const short8*)(Ab + (wm + mi * 16 + lr) * 32 + rsw);
#pragma unroll
            for (int ni = 0; ni < 4; ++ni)
                bf[ni] = *(const short8*)(Bb + (wn + ni * 16 + lr) * 32 + rsw);
            __builtin_amdgcn_s_setprio(1);
#pragma unroll
            for (int mi = 0; mi < 4; ++mi)
#pragma unroll
                for (int ni = 0; ni < 4; ++ni)
                    acc[mi][ni] = __builtin_amdgcn_mfma_f32_16x16x32_bf16(
                        af[mi], bf[ni], acc[mi][ni], 0, 0, 0);
            __builtin_amdgcn_s_setprio(0);
        }
        co += BSTRIDE; if (co == 3 * BSTRIDE) co = 0;
        po += BSTRIDE; if (po == 3 * BSTRIDE) po = 0;
    }

    if (w < 4) {
        const float PW = 0.044194173824159216f;
#pragma unroll
        for (int ni = 0; ni < 4; ++ni) {
            const int col = n0 + wn + ni * 16 + lr;
            const float bias = b0[col];
#pragma unroll
            for (int mi = 0; mi < 4; ++mi)
#pragma unroll
                for (int r = 0; r < 4; ++r)
                    out[(size_t)(m0 + wm + mi * 16 + lq * 4 + r) * DTOT + col] =
                        acc[mi][ni][r] * PW + bias;
        }
    }
}

// ---- L2: all 9 channel-GEMMs in one launch, XCD-chunked block swizzle ----
__global__ __launch_bounds__(320) void gemm_all(const unsigned short* __restrict__ Xp,
                                                const unsigned short* __restrict__ Wt,
                                                const float* __restrict__ b0,
                                                float* __restrict__ out) {
    __shared__ __align__(16) unsigned short LDS[3 * BSTRIDE];  // 72 KiB

    // T1: 8 blocks sharing an A-tile land consecutively on ONE XCD;
    // per-XCD groups interleave d5/d3/d1. Bijective: 1152 = 8*144.
    const int hw = blockIdx.x;
    const int xcd = hw & 7, j = hw >> 3;                  // j in [0,144)
    const int b = ((xcd + ((j >> 3) << 3)) << 3) + (j & 7);

    if (b < 512)       body_d35<5, 4, 2048, 2>(b, Xp, Wt, out, LDS);
    else if (b < 1024) body_d35<3, 1, 512, 1>(b - 512, Xp, Wt, out, LDS);
    else               body_d1(b - 1024, Xp, Wt, b0, out, LDS);
}

extern "C" void kernel_launch(void* const* d_in, const int* in_sizes, int n_in,
                              void* d_out, int out_size, void* d_ws, size_t ws_size,
                              hipStream_t stream) {
    const float* x  = (const float*)d_in[0];
    const float* w0 = (const float*)d_in[1];
    const float* w1 = (const float*)d_in[2];
    const float* w2 = (const float*)d_in[3];
    const float* b0 = (const float*)d_in[4];
    float* out = (float*)d_out;

    unsigned short* Xp = (unsigned short*)d_ws;
    unsigned short* Wt = (unsigned short*)((char*)d_ws + XPL_BYTES);

    prep<<<dim3(BATCH + 192), dim3(256), 0, stream>>>(x, w0, w1, w2, Xp, Wt);
    gemm_all<<<dim3(1152), dim3(320), 0, stream>>>(Xp, Wt, b0, out);
}

// Round 7
// 173.378 us; speedup vs baseline: 1.0568x; 1.0568x over previous
//
#include <hip/hip_runtime.h>

// Round 13: plane-stacked big-tile GEMM (m248 2-phase geometry).
//  The 9 channel-GEMMs become 3 stacked GEMMs with comp-MINOR row order
//  (region row = b*d + comp), so each output b-row is a contiguous span and
//  the epilogue stores dense float4s. Per-channel BM divisible by 16 and d
//  (no partial-b edges): d5 BM=160 (128 mt), d3 BM=192 (64), d1 BM=256 (16);
//  BN=256 -> 2 n-halves; BK=64; 8 waves; wave tile BM/2 x 64 (acc <=128 AGPR);
//  dbuf LDS 128KB -> 1 block/CU; 416 blocks = 8*52.
//  K-loop = proven R8 2-phase: stage(kt+1) -> counted per-wave vmcnt ->
//  barrier -> ds_read+MFMA -> lgkmcnt(0) -> barrier. 8 iters.
//  T2 both-sides XOR swizzle (8-row period, 2-way residual = free), setprio,
//  pair-preserving balanced XCD swizzle (A-pairs co-XCD, types interleaved).
//  prep: only the Xp write addresses change (comp-minor stacked rows).

#define BATCH 4096
#define DTOT 4608
#define NMUL 512

typedef __attribute__((ext_vector_type(8))) short short8;
typedef __attribute__((ext_vector_type(8))) unsigned short ushort8;
typedef __attribute__((ext_vector_type(4))) float float4v;

#define XPL_BYTES (9ull * BATCH * NMUL * 2)

__device__ __forceinline__ unsigned short f2bf(float f) {
    unsigned int u = __builtin_bit_cast(unsigned int, f);
    return (unsigned short)((u + 0x7fffu + ((u >> 16) & 1u)) >> 16);
}
__device__ __forceinline__ void gld16(const unsigned short* g, unsigned short* l) {
    __builtin_amdgcn_global_load_lds(
        (const __attribute__((address_space(1))) unsigned int*)(const void*)g,
        (__attribute__((address_space(3))) unsigned int*)(void*)l, 16, 0, 0);
}
template <int N>
__device__ __forceinline__ void waitvm() {
    asm volatile("s_waitcnt vmcnt(%0)" :: "n"(N) : "memory");
}
__device__ __forceinline__ void waitlgkm0() {
    asm volatile("s_waitcnt lgkmcnt(0)" ::: "memory");
}
__device__ __forceinline__ void colmap(int col, int& c, int& u) {
    if (col < 512)       { c = 0; u = col; }
    else if (col < 2048) { int t = col - 512;  c = 1 + t % 3; u = t / 3; }
    else                 { int t = col - 2048; c = 4 + t % 5; u = t / 5; }
}

// ---- L1: prep. Read/transpose unchanged; writes go to comp-minor stacked
// rows: ch0 row b (base 0), ch1 row 3b+comp (base 4096), ch2 row 5b+comp
// (base 16384). W-convert tiles unchanged. ----
__global__ __launch_bounds__(256) void prep(const float* __restrict__ x,
                                            const float* __restrict__ w0,
                                            const float* __restrict__ w1,
                                            const float* __restrict__ w2,
                                            unsigned short* __restrict__ Xp,
                                            unsigned short* __restrict__ Wt) {
    __shared__ unsigned short buf[4608];
    const int tid = threadIdx.x;
    const int b = blockIdx.x;
    if (b < BATCH) {
        const int row = b;
        const float4v* src = (const float4v*)(x + (size_t)row * DTOT);
        for (int p = tid; p < DTOT / 4; p += 256) {
            float4v v = src[p];
#pragma unroll
            for (int j = 0; j < 4; ++j) {
                int c, u; colmap(p * 4 + j, c, u);
                buf[c * NMUL + u] = f2bf(v[j]);
            }
        }
        __syncthreads();
        for (int q = tid; q < DTOT / 8; q += 256) {
            const int c = q >> 6, u8 = q & 63;
            size_t rowg;
            if (c == 0)      rowg = (size_t)row;
            else if (c < 4)  rowg = 4096 + (size_t)row * 3 + (c - 1);
            else             rowg = 16384 + (size_t)row * 5 + (c - 4);
            *(ushort8*)(Xp + rowg * NMUL + u8 * 8) =
                *(const ushort8*)&buf[c * NMUL + u8 * 8];
        }
    } else {
        const int t = b - BATCH;              // 0..191
        const int ch = t >> 6, tt = t & 63;
        const int tk = (tt >> 3) * 64, tn = (tt & 7) * 64;
        const float* W = (ch == 0) ? w0 : (ch == 1) ? w1 : w2;
        const int r0 = tid >> 4, c4 = (tid & 15) * 4;
#pragma unroll
        for (int rr = 0; rr < 4; ++rr) {
            const int row = r0 + rr * 16;     // k within tile
            float4v v = *(const float4v*)(W + (size_t)(tk + row) * NMUL + tn + c4);
#pragma unroll
            for (int j = 0; j < 4; ++j) buf[(c4 + j) * 72 + row] = f2bf(v[j]);
        }
        __syncthreads();
        for (int q = tid; q < 512; q += 256) {
            const int nn = q >> 3, k8 = q & 7;
            *(ushort8*)(Wt + ((size_t)(ch * NMUL + tn + nn) * NMUL) + tk + k8 * 8) =
                *(const ushort8*)&buf[nn * 72 + k8 * 8];
        }
    }
}

// ---- stacked-GEMM body: BM x 256 x K512, 8 waves, 2-phase dbuf ----
template <int D, int BM, int ROWBASE, int WCH, int XOFF>
__device__ __forceinline__ void body(int rel,
                                     const unsigned short* __restrict__ Xp,
                                     const unsigned short* __restrict__ Wt,
                                     const float* __restrict__ b0,
                                     float* __restrict__ out,
                                     unsigned short* LDS) {
    constexpr int MF = BM / 32;               // m-frags per wave (5/6/8)
    constexpr int QA = BM / 8;                // A staging quanta (20/24/32)
    const int tid = threadIdx.x;
    const int lane = tid & 63;
    const int w = tid >> 6;                   // 0..7
    const int lr = lane & 15;
    const int lq = lane >> 4;
    const int wm = (w >> 2) * (BM / 2);
    const int wn = (w & 3) * 64;

    const int n0 = (rel & 1) * 256;
    const int m0 = (rel >> 1) * BM;

    // staging: quantum = 8 rows x 128B; lane -> (row=lane>>3, chunk=lane&7),
    // source chunk pre-swizzled with row&7 (T2 both-sides)
    const int soff = (lane >> 3) * NMUL + (((lane & 7) ^ (lane >> 3)) * 8);
    const unsigned short* Ga = Xp + (size_t)(ROWBASE + m0) * NMUL;
    const unsigned short* Gb = Wt + (size_t)(WCH * 512 + n0) * NMUL;

    float4v acc[MF][4];
#pragma unroll
    for (int a = 0; a < MF; ++a)
#pragma unroll
        for (int c = 0; c < 4; ++c) acc[a][c] = (float4v)0.f;

    auto stage = [&](int kt, int buf) {
        const int ko = kt * 64;
        unsigned short* Ad = LDS + (buf ? (BM * 64) : 0);
        unsigned short* Bd = LDS + 2 * BM * 64 + (buf ? 16384 : 0);
        for (int q = w; q < QA; q += 8)
            gld16(Ga + (size_t)q * 8 * NMUL + soff + ko, Ad + q * 512);
#pragma unroll
        for (int qq = 0; qq < 4; ++qq) {
            const int qb = w * 4 + qq;
            gld16(Gb + (size_t)qb * 8 * NMUL + soff + ko, Bd + qb * 512);
        }
    };

    stage(0, 0);
    for (int kt = 0; kt < 8; ++kt) {
        const int buf = kt & 1;
        if (kt < 7) stage(kt + 1, buf ^ 1);
        // counted wait: own stage(kt) landed; stage(kt+1) stays in flight
        if (kt < 7) {
            if (D == 5) { if (w < 4) waitvm<7>(); else waitvm<6>(); }
            else if (D == 3) waitvm<7>();
            else waitvm<8>();
        } else {
            waitvm<0>();
        }
        __builtin_amdgcn_s_barrier();          // buf[kt&1] landed for everyone
        {
            const unsigned short* Al = LDS + (buf ? (BM * 64) : 0);
            const unsigned short* Bl = LDS + 2 * BM * 64 + (buf ? 16384 : 0);
#pragma unroll
            for (int kk = 0; kk < 2; ++kk) {
                const int sw = (((kk * 4 + lq) ^ (lr & 7)) * 8);
                short8 af[MF], bf[4];
#pragma unroll
                for (int mi = 0; mi < MF; ++mi)
                    af[mi] = *(const short8*)(Al + (wm + mi * 16 + lr) * 64 + sw);
#pragma unroll
                for (int ni = 0; ni < 4; ++ni)
                    bf[ni] = *(const short8*)(Bl + (wn + ni * 16 + lr) * 64 + sw);
                __builtin_amdgcn_s_setprio(1);
#pragma unroll
                for (int mi = 0; mi < MF; ++mi)
#pragma unroll
                    for (int ni = 0; ni < 4; ++ni)
                        acc[mi][ni] = __builtin_amdgcn_mfma_f32_16x16x32_bf16(
                            af[mi], bf[ni], acc[mi][ni], 0, 0, 0);
                __builtin_amdgcn_s_setprio(0);
            }
        }
        waitlgkm0();                           // reads of buf done
        __builtin_amdgcn_s_barrier();          // safe to overwrite next iter
    }

    // ---- epilogue: chunked LDS transpose -> dense float4 stores ----
    // chunk = CROWS stacked rows = CB whole b's (BM divisible by D: no edges)
    constexpr int NCH = (D == 1) ? 4 : 2;
    constexpr int CROWS = BM / NCH;            // 80 / 96 / 64
    constexpr int CB = CROWS / D;              // 16 / 32 / 64
    float* Cs = (float*)LDS;
    const float PW = 0.044194173824159216f;
    const int bstart = m0 / D;

#pragma unroll
    for (int c = 0; c < NCH; ++c) {
        // scatter: frag rows in [c*CROWS, (c+1)*CROWS) (frag-aligned)
#pragma unroll
        for (int mi = 0; mi < MF; ++mi) {
            const int fr = wm + mi * 16;
            if (fr >= c * CROWS && fr < (c + 1) * CROWS) {
#pragma unroll
                for (int r_ = 0; r_ < 4; ++r_) {
                    const int lrow = fr + lq * 4 + r_ - c * CROWS;
                    const int bl = lrow / D, comp = lrow % D;
#pragma unroll
                    for (int ni = 0; ni < 4; ++ni)
                        Cs[(size_t)(bl * 256 + wn + ni * 16 + lr) * D + comp] =
                            acc[mi][ni][r_] * PW;
                }
            }
        }
        __syncthreads();
        // write: per b a contiguous 256*D f32 span at XOFF + n0*D
        const size_t ob = (size_t)(bstart + c * CB) * DTOT + XOFF + (size_t)n0 * D;
        for (int idx = tid; idx < CB * 64 * D; idx += 512) {
            const int bl = idx / (64 * D);
            const int rem = idx - bl * (64 * D);
            float4v v = *(const float4v*)(Cs + (size_t)bl * 256 * D + rem * 4);
            if (D == 1) {
                float4v bias = *(const float4v*)(b0 + n0 + rem * 4);
                v = v + bias;
            }
            *(float4v*)(out + ob + (size_t)bl * DTOT + rem * 4) = v;
        }
        __syncthreads();
    }
}

// ---- L2: 416 blocks x 512 thr; pair-preserving balanced XCD swizzle ----
__global__ __launch_bounds__(512) void gemm_all(const unsigned short* __restrict__ Xp,
                                                const unsigned short* __restrict__ Wt,
                                                const float* __restrict__ b0,
                                                float* __restrict__ out) {
    __shared__ __align__(16) unsigned short LDS[65536];   // 128 KiB

    // HW maps block hw to XCD hw%8. Work pairs (2k,2k+1) share an A-tile:
    // put both members on the SAME XCD, round-robin pairs across XCDs for
    // type balance. 416 = 16*26: hw -> x=hw&7, s=hw>>3 (52 slots/XCD),
    // b = 16*(s>>1) + 2*x + (s&1). Bijective.
    const int hw = blockIdx.x;
    const int x = hw & 7, s = hw >> 3;
    const int b = 16 * (s >> 1) + 2 * x + (s & 1);

    if (b < 256)      body<5, 160, 16384, 2, 2048>(b, Xp, Wt, b0, out, LDS);
    else if (b < 384) body<3, 192, 4096, 1, 512>(b - 256, Xp, Wt, b0, out, LDS);
    else              body<1, 256, 0, 0, 0>(b - 384, Xp, Wt, b0, out, LDS);
}

extern "C" void kernel_launch(void* const* d_in, const int* in_sizes, int n_in,
                              void* d_out, int out_size, void* d_ws, size_t ws_size,
                              hipStream_t stream) {
    const float* x  = (const float*)d_in[0];
    const float* w0 = (const float*)d_in[1];
    const float* w1 = (const float*)d_in[2];
    const float* w2 = (const float*)d_in[3];
    const float* b0 = (const float*)d_in[4];
    float* out = (float*)d_out;

    unsigned short* Xp = (unsigned short*)d_ws;
    unsigned short* Wt = (unsigned short*)((char*)d_ws + XPL_BYTES);

    prep<<<dim3(BATCH + 192), dim3(256), 0, stream>>>(x, w0, w1, w2, Xp, Wt);
    gemm_all<<<dim3(416), dim3(512), 0, stream>>>(Xp, Wt, b0, out);
}

// Round 8
// 171.824 us; speedup vs baseline: 1.0663x; 1.0090x over previous
//
#include <hip/hip_runtime.h>

// Round 14: R13 big-tile structure at 2 blocks/CU (BN 256 -> 128).
//  R13 post-mortem: 128KB LDS -> 1 block/CU -> all 8 waves idle at each of
//  16 barriers/block with nothing co-resident; barrier-wait ~60% of block
//  time. Halving BN fits 2 blocks/CU (d5 72KB, d3 80KB, d1 64KB) so the
//  co-resident block's compute hides barrier convergence + ds_read latency.
//  Also: 896 blocks (512 d5 / 256 d3 / 128 d1-BM128) = 3.5 slots/CU,
//  tail <3% (was 416 @ 1/CU = 81% util).
//  Keeps: comp-minor stacked rows, 2-phase counted-vmcnt dbuf K-loop, T2
//  both-sides XOR swizzle, setprio, chunked LDS-transpose epilogue,
//  quad-preserving XCD swizzle. prep (L1) unchanged.

#define BATCH 4096
#define DTOT 4608
#define NMUL 512

typedef __attribute__((ext_vector_type(8))) short short8;
typedef __attribute__((ext_vector_type(8))) unsigned short ushort8;
typedef __attribute__((ext_vector_type(4))) float float4v;

#define XPL_BYTES (9ull * BATCH * NMUL * 2)

__device__ __forceinline__ unsigned short f2bf(float f) {
    unsigned int u = __builtin_bit_cast(unsigned int, f);
    return (unsigned short)((u + 0x7fffu + ((u >> 16) & 1u)) >> 16);
}
__device__ __forceinline__ void gld16(const unsigned short* g, unsigned short* l) {
    __builtin_amdgcn_global_load_lds(
        (const __attribute__((address_space(1))) unsigned int*)(const void*)g,
        (__attribute__((address_space(3))) unsigned int*)(void*)l, 16, 0, 0);
}
template <int N>
__device__ __forceinline__ void waitvm() {
    asm volatile("s_waitcnt vmcnt(%0)" :: "n"(N) : "memory");
}
__device__ __forceinline__ void waitlgkm0() {
    asm volatile("s_waitcnt lgkmcnt(0)" ::: "memory");
}
__device__ __forceinline__ void colmap(int col, int& c, int& u) {
    if (col < 512)       { c = 0; u = col; }
    else if (col < 2048) { int t = col - 512;  c = 1 + t % 3; u = t / 3; }
    else                 { int t = col - 2048; c = 4 + t % 5; u = t / 5; }
}

// ---- L1: prep — unchanged from R13 (comp-minor stacked row writes) ----
__global__ __launch_bounds__(256) void prep(const float* __restrict__ x,
                                            const float* __restrict__ w0,
                                            const float* __restrict__ w1,
                                            const float* __restrict__ w2,
                                            unsigned short* __restrict__ Xp,
                                            unsigned short* __restrict__ Wt) {
    __shared__ unsigned short buf[4608];
    const int tid = threadIdx.x;
    const int b = blockIdx.x;
    if (b < BATCH) {
        const int row = b;
        const float4v* src = (const float4v*)(x + (size_t)row * DTOT);
        for (int p = tid; p < DTOT / 4; p += 256) {
            float4v v = src[p];
#pragma unroll
            for (int j = 0; j < 4; ++j) {
                int c, u; colmap(p * 4 + j, c, u);
                buf[c * NMUL + u] = f2bf(v[j]);
            }
        }
        __syncthreads();
        for (int q = tid; q < DTOT / 8; q += 256) {
            const int c = q >> 6, u8 = q & 63;
            size_t rowg;
            if (c == 0)      rowg = (size_t)row;
            else if (c < 4)  rowg = 4096 + (size_t)row * 3 + (c - 1);
            else             rowg = 16384 + (size_t)row * 5 + (c - 4);
            *(ushort8*)(Xp + rowg * NMUL + u8 * 8) =
                *(const ushort8*)&buf[c * NMUL + u8 * 8];
        }
    } else {
        const int t = b - BATCH;              // 0..191
        const int ch = t >> 6, tt = t & 63;
        const int tk = (tt >> 3) * 64, tn = (tt & 7) * 64;
        const float* W = (ch == 0) ? w0 : (ch == 1) ? w1 : w2;
        const int r0 = tid >> 4, c4 = (tid & 15) * 4;
#pragma unroll
        for (int rr = 0; rr < 4; ++rr) {
            const int row = r0 + rr * 16;     // k within tile
            float4v v = *(const float4v*)(W + (size_t)(tk + row) * NMUL + tn + c4);
#pragma unroll
            for (int j = 0; j < 4; ++j) buf[(c4 + j) * 72 + row] = f2bf(v[j]);
        }
        __syncthreads();
        for (int q = tid; q < 512; q += 256) {
            const int nn = q >> 3, k8 = q & 7;
            *(ushort8*)(Wt + ((size_t)(ch * NMUL + tn + nn) * NMUL) + tk + k8 * 8) =
                *(const ushort8*)&buf[nn * 72 + k8 * 8];
        }
    }
}

// ---- stacked-GEMM body: BM x 128 x K512, 8 waves (2m x 4n), 2-ph dbuf ----
template <int D, int BM, int ROWBASE, int WCH, int XOFF>
__device__ __forceinline__ void body(int rel,
                                     const unsigned short* __restrict__ Xp,
                                     const unsigned short* __restrict__ Wt,
                                     const float* __restrict__ b0,
                                     float* __restrict__ out,
                                     unsigned short* LDS) {
    constexpr int MF = BM / 32;               // m-frags per wave (5/6/4)
    constexpr int QA = BM / 8;                // A staging quanta (20/24/16)
    constexpr int ABUF = BM * 64;             // u16 per A buffer
    const int tid = threadIdx.x;
    const int lane = tid & 63;
    const int w = tid >> 6;                   // 0..7
    const int lr = lane & 15;
    const int lq = lane >> 4;
    const int wm = (w >> 2) * (BM / 2);
    const int wn = (w & 3) * 32;

    const int n0 = (rel & 3) * 128;
    const int m0 = (rel >> 2) * BM;

    // staging quantum: 8 rows x 128B; source chunk pre-swizzled by row&7 (T2)
    const int soff = (lane >> 3) * NMUL + (((lane & 7) ^ (lane >> 3)) * 8);
    const unsigned short* Ga = Xp + (size_t)(ROWBASE + m0) * NMUL;
    const unsigned short* Gb = Wt + (size_t)(WCH * 512 + n0) * NMUL;

    float4v acc[MF][2];
#pragma unroll
    for (int a = 0; a < MF; ++a)
#pragma unroll
        for (int c = 0; c < 2; ++c) acc[a][c] = (float4v)0.f;

    auto stage = [&](int kt, int buf) {
        const int ko = kt * 64;
        unsigned short* Ad = LDS + (buf ? ABUF : 0);
        unsigned short* Bd = LDS + 2 * ABUF + (buf ? 8192 : 0);
        for (int q = w; q < QA; q += 8)
            gld16(Ga + (size_t)q * 8 * NMUL + soff + ko, Ad + q * 512);
#pragma unroll
        for (int qq = 0; qq < 2; ++qq) {
            const int qb = w * 2 + qq;
            gld16(Gb + (size_t)qb * 8 * NMUL + soff + ko, Bd + qb * 512);
        }
    };

    stage(0, 0);
    for (int kt = 0; kt < 8; ++kt) {
        const int buf = kt & 1;
        if (kt < 7) stage(kt + 1, buf ^ 1);
        // counted wait: stage(kt) landed; stage(kt+1) stays in flight
        if (kt < 7) {
            if (D == 5) { if (w < 4) waitvm<5>(); else waitvm<4>(); }
            else if (D == 3) waitvm<5>();
            else waitvm<4>();
        } else {
            waitvm<0>();
        }
        __builtin_amdgcn_s_barrier();          // buf[kt&1] landed for everyone
        {
            const unsigned short* Al = LDS + (buf ? ABUF : 0);
            const unsigned short* Bl = LDS + 2 * ABUF + (buf ? 8192 : 0);
#pragma unroll
            for (int kk = 0; kk < 2; ++kk) {
                const int sw = (((kk * 4 + lq) ^ (lr & 7)) * 8);
                short8 af[MF], bf[2];
#pragma unroll
                for (int mi = 0; mi < MF; ++mi)
                    af[mi] = *(const short8*)(Al + (wm + mi * 16 + lr) * 64 + sw);
#pragma unroll
                for (int ni = 0; ni < 2; ++ni)
                    bf[ni] = *(const short8*)(Bl + (wn + ni * 16 + lr) * 64 + sw);
                __builtin_amdgcn_s_setprio(1);
#pragma unroll
                for (int mi = 0; mi < MF; ++mi)
#pragma unroll
                    for (int ni = 0; ni < 2; ++ni)
                        acc[mi][ni] = __builtin_amdgcn_mfma_f32_16x16x32_bf16(
                            af[mi], bf[ni], acc[mi][ni], 0, 0, 0);
                __builtin_amdgcn_s_setprio(0);
            }
        }
        waitlgkm0();                           // reads of buf done
        __builtin_amdgcn_s_barrier();          // safe to overwrite next iter
    }

    // ---- epilogue: chunked LDS transpose -> dense float4 stores ----
    constexpr int NCH = 2;
    constexpr int CROWS = BM / NCH;            // 80 / 96 / 64
    constexpr int CB = CROWS / D;              // 16 / 32 / 64
    float* Cs = (float*)LDS;
    const float PW = 0.044194173824159216f;
    const int bstart = m0 / D;

#pragma unroll
    for (int c = 0; c < NCH; ++c) {
#pragma unroll
        for (int mi = 0; mi < MF; ++mi) {
            const int fr = wm + mi * 16;
            if (fr >= c * CROWS && fr < (c + 1) * CROWS) {
#pragma unroll
                for (int r_ = 0; r_ < 4; ++r_) {
                    const int lrow = fr + lq * 4 + r_ - c * CROWS;
                    const int bl = lrow / D, comp = lrow % D;
#pragma unroll
                    for (int ni = 0; ni < 2; ++ni)
                        Cs[(size_t)(bl * 128 + wn + ni * 16 + lr) * D + comp] =
                            acc[mi][ni][r_] * PW;
                }
            }
        }
        __syncthreads();
        // per b: contiguous 128*D f32 span at XOFF + n0*D
        const size_t ob = (size_t)(bstart + c * CB) * DTOT + XOFF + (size_t)n0 * D;
        for (int idx = tid; idx < CB * 32 * D; idx += 512) {
            const int bl = idx / (32 * D);
            const int rem = idx - bl * (32 * D);
            float4v v = *(const float4v*)(Cs + (size_t)bl * 128 * D + rem * 4);
            if (D == 1) {
                float4v bias = *(const float4v*)(b0 + n0 + rem * 4);
                v = v + bias;
            }
            *(float4v*)(out + ob + (size_t)bl * DTOT + rem * 4) = v;
        }
        __syncthreads();
    }
}

// ---- L2: 896 blocks x 512 thr; quad-preserving XCD swizzle ----
__global__ __launch_bounds__(512) void gemm_all(const unsigned short* __restrict__ Xp,
                                                const unsigned short* __restrict__ Wt,
                                                const float* __restrict__ b0,
                                                float* __restrict__ out) {
    __shared__ __align__(16) unsigned short LDS[40960];   // 80 KiB -> 2 blocks/CU

    // Work quads (4k..4k+3) share an A-tile: keep them on ONE XCD.
    // 896 = 8 * 112; g = x + 8*(s>>2) in [0,224), b = 4g + (s&3). Bijective.
    const int hw = blockIdx.x;
    const int x = hw & 7, s = hw >> 3;
    const int g = x + ((s >> 2) << 3);
    const int b = (g << 2) | (s & 3);

    if (b < 512)      body<5, 160, 16384, 2, 2048>(b, Xp, Wt, b0, out, LDS);
    else if (b < 768) body<3, 192, 4096, 1, 512>(b - 512, Xp, Wt, b0, out, LDS);
    else              body<1, 128, 0, 0, 0>(b - 768, Xp, Wt, b0, out, LDS);
}

extern "C" void kernel_launch(void* const* d_in, const int* in_sizes, int n_in,
                              void* d_out, int out_size, void* d_ws, size_t ws_size,
                              hipStream_t stream) {
    const float* x  = (const float*)d_in[0];
    const float* w0 = (const float*)d_in[1];
    const float* w1 = (const float*)d_in[2];
    const float* w2 = (const float*)d_in[3];
    const float* b0 = (const float*)d_in[4];
    float* out = (float*)d_out;

    unsigned short* Xp = (unsigned short*)d_ws;
    unsigned short* Wt = (unsigned short*)((char*)d_ws + XPL_BYTES);

    prep<<<dim3(BATCH + 192), dim3(256), 0, stream>>>(x, w0, w1, w2, Xp, Wt);
    gemm_all<<<dim3(896), dim3(512), 0, stream>>>(Xp, Wt, b0, out);
}

// Round 10
// 170.752 us; speedup vs baseline: 1.0730x; 1.0063x over previous
//
#include <hip/hip_runtime.h>

// Round 15b: resubmit of R15 (container infra failure, kernel never ran).
//  prep rewritten as barrier-free register deinterleave; gemm = R13 verbatim
//  (champion, 45.8 us profiled).
//  prep insight: 12 consecutive ch1 floats = 4 complete (u,comp) triples ->
//  3 packed ushort4 stores (one per comp-row); 20 consecutive ch2 floats =
//  4 complete 5-tuples -> 5 ushort4 stores; ch0 = 1 ushort8. 320 thr/row
//  (64 ch0 + 128 ch1 + 128 ch2): no LDS, no barriers, no div/mod (u0=4g).
//  Loads: contiguous per-wave streams; stores: contiguous per comp-row
//  streams. W-convert blocks unchanged (tid<256 guard).
//  Accounting across R7-R14: fills 91 (harness) + prep ~35 + gemm ~46;
//  prep floor is 18 us -> this targets the largest untouched term.

#define BATCH 4096
#define DTOT 4608
#define NMUL 512

typedef __attribute__((ext_vector_type(8))) short short8;
typedef __attribute__((ext_vector_type(8))) unsigned short ushort8;
typedef __attribute__((ext_vector_type(4))) unsigned short ushort4v;
typedef __attribute__((ext_vector_type(4))) float float4v;

#define XPL_BYTES (9ull * BATCH * NMUL * 2)

__device__ __forceinline__ unsigned short f2bf(float f) {
    unsigned int u = __builtin_bit_cast(unsigned int, f);
    return (unsigned short)((u + 0x7fffu + ((u >> 16) & 1u)) >> 16);
}
__device__ __forceinline__ void gld16(const unsigned short* g, unsigned short* l) {
    __builtin_amdgcn_global_load_lds(
        (const __attribute__((address_space(1))) unsigned int*)(const void*)g,
        (__attribute__((address_space(3))) unsigned int*)(void*)l, 16, 0, 0);
}
template <int N>
__device__ __forceinline__ void waitvm() {
    asm volatile("s_waitcnt vmcnt(%0)" :: "n"(N) : "memory");
}
__device__ __forceinline__ void waitlgkm0() {
    asm volatile("s_waitcnt lgkmcnt(0)" ::: "memory");
}

// ---- L1: prep. x-rows: register deinterleave, no LDS/barriers/divides.
//      W-tiles: verified LDS transpose (tid<256). 320 threads/block. ----
__global__ __launch_bounds__(320) void prep(const float* __restrict__ x,
                                            const float* __restrict__ w0,
                                            const float* __restrict__ w1,
                                            const float* __restrict__ w2,
                                            unsigned short* __restrict__ Xp,
                                            unsigned short* __restrict__ Wt) {
    __shared__ unsigned short buf[4608];
    const int tid = threadIdx.x;
    const int b = blockIdx.x;
    if (b < BATCH) {
        const int r = b;
        const float* xr = x + (size_t)r * DTOT;
        if (tid < 64) {
            // ch0 (0e): 8 consecutive cols -> 1 ushort8, row r
            const int g = tid;
            float4v v0 = *(const float4v*)(xr + g * 8);
            float4v v1 = *(const float4v*)(xr + g * 8 + 4);
            ushort8 o;
#pragma unroll
            for (int j = 0; j < 4; ++j) {
                o[j] = f2bf(v0[j]);
                o[4 + j] = f2bf(v1[j]);
            }
            *(ushort8*)(Xp + (size_t)r * NMUL + g * 8) = o;
        } else if (tid < 192) {
            // ch1 (1e): 12 consecutive floats = u0..u0+3 x comp0..2
            const int g = tid - 64;               // 0..127, u0 = 4g
            const float* s = xr + 512 + g * 12;
            float4v va = *(const float4v*)s;
            float4v vb = *(const float4v*)(s + 4);
            float4v vc = *(const float4v*)(s + 8);
            float e[12];
#pragma unroll
            for (int j = 0; j < 4; ++j) {
                e[j] = va[j]; e[4 + j] = vb[j]; e[8 + j] = vc[j];
            }
#pragma unroll
            for (int c = 0; c < 3; ++c) {
                ushort4v o = { f2bf(e[c]), f2bf(e[c + 3]),
                               f2bf(e[c + 6]), f2bf(e[c + 9]) };
                *(ushort4v*)(Xp + (size_t)(4096 + 3 * r + c) * NMUL + g * 4) = o;
            }
        } else {
            // ch2 (2e): 20 consecutive floats = u0..u0+3 x comp0..4
            const int g = tid - 192;              // 0..127, u0 = 4g
            const float* s = xr + 2048 + g * 20;
            float4v v[5];
#pragma unroll
            for (int q = 0; q < 5; ++q) v[q] = *(const float4v*)(s + q * 4);
            float e[20];
#pragma unroll
            for (int q = 0; q < 5; ++q)
#pragma unroll
                for (int j = 0; j < 4; ++j) e[q * 4 + j] = v[q][j];
#pragma unroll
            for (int c = 0; c < 5; ++c) {
                ushort4v o = { f2bf(e[c]), f2bf(e[c + 5]),
                               f2bf(e[c + 10]), f2bf(e[c + 15]) };
                *(ushort4v*)(Xp + (size_t)(16384 + 5 * r + c) * NMUL + g * 4) = o;
            }
        }
    } else {
        const int t = b - BATCH;              // 0..191
        const int ch = t >> 6, tt = t & 63;
        const int tk = (tt >> 3) * 64, tn = (tt & 7) * 64;
        const float* W = (ch == 0) ? w0 : (ch == 1) ? w1 : w2;
        if (tid < 256) {
            const int r0 = tid >> 4, c4 = (tid & 15) * 4;
#pragma unroll
            for (int rr = 0; rr < 4; ++rr) {
                const int row = r0 + rr * 16;     // k within tile
                float4v v = *(const float4v*)(W + (size_t)(tk + row) * NMUL + tn + c4);
#pragma unroll
                for (int j = 0; j < 4; ++j) buf[(c4 + j) * 72 + row] = f2bf(v[j]);
            }
        }
        __syncthreads();
        if (tid < 256) {
            for (int q = tid; q < 512; q += 256) {
                const int nn = q >> 3, k8 = q & 7;
                *(ushort8*)(Wt + ((size_t)(ch * NMUL + tn + nn) * NMUL) + tk + k8 * 8) =
                    *(const ushort8*)&buf[nn * 72 + k8 * 8];
            }
        }
    }
}

// ---- stacked-GEMM body: BM x 256 x K512, 8 waves, 2-phase dbuf (R13) ----
template <int D, int BM, int ROWBASE, int WCH, int XOFF>
__device__ __forceinline__ void body(int rel,
                                     const unsigned short* __restrict__ Xp,
                                     const unsigned short* __restrict__ Wt,
                                     const float* __restrict__ b0,
                                     float* __restrict__ out,
                                     unsigned short* LDS) {
    constexpr int MF = BM / 32;               // m-frags per wave (5/6/8)
    constexpr int QA = BM / 8;                // A staging quanta (20/24/32)
    const int tid = threadIdx.x;
    const int lane = tid & 63;
    const int w = tid >> 6;                   // 0..7
    const int lr = lane & 15;
    const int lq = lane >> 4;
    const int wm = (w >> 2) * (BM / 2);
    const int wn = (w & 3) * 64;

    const int n0 = (rel & 1) * 256;
    const int m0 = (rel >> 1) * BM;

    // staging: quantum = 8 rows x 128B; lane -> (row=lane>>3, chunk=lane&7),
    // source chunk pre-swizzled with row&7 (T2 both-sides)
    const int soff = (lane >> 3) * NMUL + (((lane & 7) ^ (lane >> 3)) * 8);
    const unsigned short* Ga = Xp + (size_t)(ROWBASE + m0) * NMUL;
    const unsigned short* Gb = Wt + (size_t)(WCH * 512 + n0) * NMUL;

    float4v acc[MF][4];
#pragma unroll
    for (int a = 0; a < MF; ++a)
#pragma unroll
        for (int c = 0; c < 4; ++c) acc[a][c] = (float4v)0.f;

    auto stage = [&](int kt, int buf) {
        const int ko = kt * 64;
        unsigned short* Ad = LDS + (buf ? (BM * 64) : 0);
        unsigned short* Bd = LDS + 2 * BM * 64 + (buf ? 16384 : 0);
        for (int q = w; q < QA; q += 8)
            gld16(Ga + (size_t)q * 8 * NMUL + soff + ko, Ad + q * 512);
#pragma unroll
        for (int qq = 0; qq < 4; ++qq) {
            const int qb = w * 4 + qq;
            gld16(Gb + (size_t)qb * 8 * NMUL + soff + ko, Bd + qb * 512);
        }
    };

    stage(0, 0);
    for (int kt = 0; kt < 8; ++kt) {
        const int buf = kt & 1;
        if (kt < 7) stage(kt + 1, buf ^ 1);
        // counted wait: own stage(kt) landed; stage(kt+1) stays in flight
        if (kt < 7) {
            if (D == 5) { if (w < 4) waitvm<7>(); else waitvm<6>(); }
            else if (D == 3) waitvm<7>();
            else waitvm<8>();
        } else {
            waitvm<0>();
        }
        __builtin_amdgcn_s_barrier();          // buf[kt&1] landed for everyone
        {
            const unsigned short* Al = LDS + (buf ? (BM * 64) : 0);
            const unsigned short* Bl = LDS + 2 * BM * 64 + (buf ? 16384 : 0);
#pragma unroll
            for (int kk = 0; kk < 2; ++kk) {
                const int sw = (((kk * 4 + lq) ^ (lr & 7)) * 8);
                short8 af[MF], bf[4];
#pragma unroll
                for (int mi = 0; mi < MF; ++mi)
                    af[mi] = *(const short8*)(Al + (wm + mi * 16 + lr) * 64 + sw);
#pragma unroll
                for (int ni = 0; ni < 4; ++ni)
                    bf[ni] = *(const short8*)(Bl + (wn + ni * 16 + lr) * 64 + sw);
                __builtin_amdgcn_s_setprio(1);
#pragma unroll
                for (int mi = 0; mi < MF; ++mi)
#pragma unroll
                    for (int ni = 0; ni < 4; ++ni)
                        acc[mi][ni] = __builtin_amdgcn_mfma_f32_16x16x32_bf16(
                            af[mi], bf[ni], acc[mi][ni], 0, 0, 0);
                __builtin_amdgcn_s_setprio(0);
            }
        }
        waitlgkm0();                           // reads of buf done
        __builtin_amdgcn_s_barrier();          // safe to overwrite next iter
    }

    // ---- epilogue: chunked LDS transpose -> dense float4 stores ----
    constexpr int NCH = (D == 1) ? 4 : 2;
    constexpr int CROWS = BM / NCH;            // 80 / 96 / 64
    constexpr int CB = CROWS / D;              // 16 / 32 / 64
    float* Cs = (float*)LDS;
    const float PW = 0.044194173824159216f;
    const int bstart = m0 / D;

#pragma unroll
    for (int c = 0; c < NCH; ++c) {
#pragma unroll
        for (int mi = 0; mi < MF; ++mi) {
            const int fr = wm + mi * 16;
            if (fr >= c * CROWS && fr < (c + 1) * CROWS) {
#pragma unroll
                for (int r_ = 0; r_ < 4; ++r_) {
                    const int lrow = fr + lq * 4 + r_ - c * CROWS;
                    const int bl = lrow / D, comp = lrow % D;
#pragma unroll
                    for (int ni = 0; ni < 4; ++ni)
                        Cs[(size_t)(bl * 256 + wn + ni * 16 + lr) * D + comp] =
                            acc[mi][ni][r_] * PW;
                }
            }
        }
        __syncthreads();
        // write: per b a contiguous 256*D f32 span at XOFF + n0*D
        const size_t ob = (size_t)(bstart + c * CB) * DTOT + XOFF + (size_t)n0 * D;
        for (int idx = tid; idx < CB * 64 * D; idx += 512) {
            const int bl = idx / (64 * D);
            const int rem = idx - bl * (64 * D);
            float4v v = *(const float4v*)(Cs + (size_t)bl * 256 * D + rem * 4);
            if (D == 1) {
                float4v bias = *(const float4v*)(b0 + n0 + rem * 4);
                v = v + bias;
            }
            *(float4v*)(out + ob + (size_t)bl * DTOT + rem * 4) = v;
        }
        __syncthreads();
    }
}

// ---- L2: 416 blocks x 512 thr; pair-preserving balanced XCD swizzle ----
__global__ __launch_bounds__(512) void gemm_all(const unsigned short* __restrict__ Xp,
                                                const unsigned short* __restrict__ Wt,
                                                const float* __restrict__ b0,
                                                float* __restrict__ out) {
    __shared__ __align__(16) unsigned short LDS[65536];   // 128 KiB

    // Work pairs (2k,2k+1) share an A-tile: both on the SAME XCD,
    // pairs round-robin across XCDs. 416 = 16*26. Bijective.
    const int hw = blockIdx.x;
    const int x = hw & 7, s = hw >> 3;
    const int b = 16 * (s >> 1) + 2 * x + (s & 1);

    if (b < 256)      body<5, 160, 16384, 2, 2048>(b, Xp, Wt, b0, out, LDS);
    else if (b < 384) body<3, 192, 4096, 1, 512>(b - 256, Xp, Wt, b0, out, LDS);
    else              body<1, 256, 0, 0, 0>(b - 384, Xp, Wt, b0, out, LDS);
}

extern "C" void kernel_launch(void* const* d_in, const int* in_sizes, int n_in,
                              void* d_out, int out_size, void* d_ws, size_t ws_size,
                              hipStream_t stream) {
    const float* x  = (const float*)d_in[0];
    const float* w0 = (const float*)d_in[1];
    const float* w1 = (const float*)d_in[2];
    const float* w2 = (const float*)d_in[3];
    const float* b0 = (const float*)d_in[4];
    float* out = (float*)d_out;

    unsigned short* Xp = (unsigned short*)d_ws;
    unsigned short* Wt = (unsigned short*)((char*)d_ws + XPL_BYTES);

    prep<<<dim3(BATCH + 192), dim3(320), 0, stream>>>(x, w0, w1, w2, Xp, Wt);
    gemm_all<<<dim3(416), dim3(512), 0, stream>>>(Xp, Wt, b0, out);
}